// Round 1
// baseline (1824.142 us; speedup 1.0000x reference)
//
#include <hip/hip_runtime.h>

#define B_ 8
#define N_ 1024
#define C1_ 64
#define C2_ 128
#define K_ 1024
#define EPS_ 1e-5f
#define XTOL_ 1e-7f

// workspace offsets (in floats)
#define OFF_G     0          // 8*16
#define OFF_DX    128        // 48
#define OFF_F0    256        // 8192
#define OFF_IDX   8448       // 8192 ints
#define OFF_ACT1  16640      // 8*64*1024
#define OFF_ACT2  540928     // 8*128*1024
#define OFF_J     1589504    // 8*1024*6
#define OFF_PINV  1638656    // 8*6*1024
// total 1687808 floats = 6.75 MB

__global__ void k_init_g(float* __restrict__ g) {
    int t = threadIdx.x;
    if (t < B_ * 16) {
        int i = t & 15;
        g[t] = (i == 0 || i == 5 || i == 10 || i == 15) ? 1.f : 0.f;
    }
}

// layer1 fused with SE(3) transform: act1[b,o,n] = relu(bn(W1 @ (R p + t) + b1))
__global__ void k_layer1(const float* __restrict__ pts, const float* __restrict__ g,
                         const float* __restrict__ W1, const float* __restrict__ b1,
                         const float* __restrict__ ga, const float* __restrict__ be,
                         const float* __restrict__ rm, const float* __restrict__ rv,
                         float* __restrict__ act1) {
    int b = blockIdx.y;
    int n = blockIdx.x * blockDim.x + threadIdx.x;
    const float* gb = g + b * 16;
    float px = pts[(b * N_ + n) * 3 + 0];
    float py = pts[(b * N_ + n) * 3 + 1];
    float pz = pts[(b * N_ + n) * 3 + 2];
    float q0 = gb[0]*px + gb[1]*py + gb[2]*pz  + gb[3];
    float q1 = gb[4]*px + gb[5]*py + gb[6]*pz  + gb[7];
    float q2 = gb[8]*px + gb[9]*py + gb[10]*pz + gb[11];
    for (int o = 0; o < C1_; ++o) {
        float acc = W1[o*3+0]*q0 + W1[o*3+1]*q1 + W1[o*3+2]*q2 + b1[o];
        float sc = ga[o] * rsqrtf(rv[o] + EPS_);
        float y = sc * (acc - rm[o]) + be[o];
        act1[(b * C1_ + o) * N_ + n] = fmaxf(y, 0.f);
    }
}

// layer2: act2[b,o,n] = relu(bn(W2 @ act1 + b2)); one thread per n, 64-reg input cache
__global__ void k_layer2(const float* __restrict__ act1,
                         const float* __restrict__ W2, const float* __restrict__ b2,
                         const float* __restrict__ ga, const float* __restrict__ be,
                         const float* __restrict__ rm, const float* __restrict__ rv,
                         float* __restrict__ act2) {
    int b = blockIdx.y;
    int n = blockIdx.x * blockDim.x + threadIdx.x;
    float in[C1_];
    #pragma unroll
    for (int c = 0; c < C1_; ++c) in[c] = act1[(b * C1_ + c) * N_ + n];
    for (int o = 0; o < C2_; ++o) {
        float acc = b2[o];
        #pragma unroll
        for (int c = 0; c < C1_; ++c) acc += W2[o * C1_ + c] * in[c];
        float sc = ga[o] * rsqrtf(rv[o] + EPS_);
        float y = sc * (acc - rm[o]) + be[o];
        act2[(b * C2_ + o) * N_ + n] = fmaxf(y, 0.f);
    }
}

// layer3 + BN + ReLU + max over n (+ argmax for MODE 0 / r=f-f0 for MODE 1)
// block 128 threads, o-tile 32, n-chunk 64, microtile 4x4
template <int MODE>
__global__ __launch_bounds__(128)
void k_layer3(const float* __restrict__ act2,
              const float* __restrict__ W3, const float* __restrict__ b3,
              const float* __restrict__ ga, const float* __restrict__ be,
              const float* __restrict__ rm, const float* __restrict__ rv,
              const float* __restrict__ f0, float* __restrict__ out,
              int* __restrict__ out_idx) {
    __shared__ float w3s[C2_][36];   // [c][o] transposed, padded for banks/alignment
    __shared__ float bs[C2_][64];    // [c][n]
    __shared__ float redv[32][16];
    __shared__ int   redi[32][16];

    int b = blockIdx.y;
    int o0 = blockIdx.x * 32;
    int tx = threadIdx.x;
    int og = tx >> 4;       // 0..7  -> o = o0 + og*4 + i
    int ng = tx & 15;       // 0..15 -> n = nbase + ng*4 + j

    // load W3 tile transposed into LDS (once)
    #pragma unroll
    for (int pass = 0; pass < 8; ++pass) {
        int o = (tx >> 5) + pass * 4;        // 0..31
        int c4 = (tx & 31) * 4;
        float4 w = *(const float4*)&W3[(o0 + o) * C2_ + c4];
        w3s[c4 + 0][o] = w.x;
        w3s[c4 + 1][o] = w.y;
        w3s[c4 + 2][o] = w.z;
        w3s[c4 + 3][o] = w.w;
    }

    float vmax[4];
    int   vidx[4];
    #pragma unroll
    for (int i = 0; i < 4; ++i) { vmax[i] = -3.4e38f; vidx[i] = 0; }

    for (int ch = 0; ch < 16; ++ch) {
        int nbase = ch * 64;
        __syncthreads();
        // stage act2 chunk: 128c x 64n
        #pragma unroll
        for (int p = 0; p < 16; ++p) {
            int idx = p * 128 + tx;          // 0..2047 float4 slots
            int c = idx >> 4;
            int n4 = (idx & 15) * 4;
            *(float4*)&bs[c][n4] = *(const float4*)&act2[(b * C2_ + c) * N_ + nbase + n4];
        }
        __syncthreads();

        float acc[4][4] = {};
        #pragma unroll 8
        for (int c = 0; c < C2_; ++c) {
            float4 a  = *(const float4*)&w3s[c][og * 4];
            float4 bb = *(const float4*)&bs[c][ng * 4];
            acc[0][0] += a.x * bb.x; acc[0][1] += a.x * bb.y; acc[0][2] += a.x * bb.z; acc[0][3] += a.x * bb.w;
            acc[1][0] += a.y * bb.x; acc[1][1] += a.y * bb.y; acc[1][2] += a.y * bb.z; acc[1][3] += a.y * bb.w;
            acc[2][0] += a.z * bb.x; acc[2][1] += a.z * bb.y; acc[2][2] += a.z * bb.z; acc[2][3] += a.z * bb.w;
            acc[3][0] += a.w * bb.x; acc[3][1] += a.w * bb.y; acc[3][2] += a.w * bb.z; acc[3][3] += a.w * bb.w;
        }

        #pragma unroll
        for (int i = 0; i < 4; ++i) {
            int o = o0 + og * 4 + i;
            float sc = ga[o] * rsqrtf(rv[o] + EPS_);
            float bo = b3[o], rmo = rm[o], beo = be[o];
            #pragma unroll
            for (int j = 0; j < 4; ++j) {
                float y = fmaxf(sc * ((acc[i][j] + bo) - rmo) + beo, 0.f);
                int n = nbase + ng * 4 + j;
                if (y > vmax[i]) { vmax[i] = y; vidx[i] = n; }  // strict > keeps first idx
            }
        }
    }

    __syncthreads();
    #pragma unroll
    for (int i = 0; i < 4; ++i) {
        redv[og * 4 + i][ng] = vmax[i];
        redi[og * 4 + i][ng] = vidx[i];
    }
    __syncthreads();
    if (tx < 32) {
        int o = o0 + tx;
        float bv = redv[tx][0];
        int bi = redi[tx][0];
        for (int q = 1; q < 16; ++q) {
            float v = redv[tx][q];
            int ii = redi[tx][q];
            if (v > bv || (v == bv && ii < bi)) { bv = v; bi = ii; }
        }
        if (MODE == 0) {
            out[b * K_ + o] = bv;
            out_idx[b * K_ + o] = bi;
        } else {
            out[b * K_ + o] = bv - f0[b * K_ + o];
        }
    }
}

// Analytical Jacobian row per (b,k), gathered at n* = argmax:
// fjg_i = D3 * sum_c (W1[c,i]*d1[c]*mask1) * (sum_d W3[k,d]*d2[d]*mask2*W2[d,c])
__global__ void k_jac(const float* __restrict__ p0,
                      const float* __restrict__ act1, const float* __restrict__ act2,
                      const float* __restrict__ W1, const float* __restrict__ ga1, const float* __restrict__ rv1,
                      const float* __restrict__ W2, const float* __restrict__ ga2, const float* __restrict__ rv2,
                      const float* __restrict__ W3, const float* __restrict__ ga3, const float* __restrict__ rv3,
                      const float* __restrict__ f0, const int* __restrict__ max_idx,
                      float* __restrict__ J) {
    int gid = blockIdx.x * blockDim.x + threadIdx.x;   // 8192
    int b = gid >> 10;
    int k = gid & 1023;
    int ns = max_idx[b * K_ + k];
    float d3 = ga3[k] * rsqrtf(rv3[k] + EPS_);
    float D3 = (f0[b * K_ + k] > 0.f) ? d3 : 0.f;

    float v[C1_];
    #pragma unroll
    for (int c = 0; c < C1_; ++c) v[c] = 0.f;

    for (int d = 0; d < C2_; ++d) {
        float a2 = act2[(b * C2_ + d) * N_ + ns];
        float wd = (a2 > 0.f) ? W3[k * C2_ + d] * ga2[d] * rsqrtf(rv2[d] + EPS_) : 0.f;
        #pragma unroll
        for (int c = 0; c < C1_; ++c) v[c] += wd * W2[d * C1_ + c];
    }

    float fj0 = 0.f, fj1 = 0.f, fj2 = 0.f;
    #pragma unroll
    for (int c = 0; c < C1_; ++c) {
        float a1 = act1[(b * C1_ + c) * N_ + ns];
        float m = (a1 > 0.f) ? ga1[c] * rsqrtf(rv1[c] + EPS_) : 0.f;
        float vc = v[c] * m;
        fj0 += vc * W1[c * 3 + 0];
        fj1 += vc * W1[c * 3 + 1];
        fj2 += vc * W1[c * 3 + 2];
    }
    fj0 *= D3; fj1 *= D3; fj2 *= D3;

    float x = p0[(b * N_ + ns) * 3 + 0];
    float y = p0[(b * N_ + ns) * 3 + 1];
    float z = p0[(b * N_ + ns) * 3 + 2];
    // wg = [-skew(p0) | -I]
    float* Jr = J + (b * K_ + k) * 6;
    Jr[0] = fj1 * (-z) + fj2 * y;
    Jr[1] = fj0 * z    + fj2 * (-x);
    Jr[2] = fj0 * (-y) + fj1 * x;
    Jr[3] = -fj0;
    Jr[4] = -fj1;
    Jr[5] = -fj2;
}

// per-b: H = J^T J (6x6), invert (Gauss-Jordan w/ partial pivot), pinv = Hinv @ J^T
__global__ void k_hpinv(const float* __restrict__ J, float* __restrict__ pinv) {
    int b = blockIdx.x;
    int tx = threadIdx.x;
    __shared__ float red[256][22];
    __shared__ float hinv[36];

    float h[21];
    #pragma unroll
    for (int q = 0; q < 21; ++q) h[q] = 0.f;
    for (int k = tx; k < K_; k += 256) {
        const float* Jr = J + (b * K_ + k) * 6;
        float j0 = Jr[0], j1 = Jr[1], j2 = Jr[2], j3 = Jr[3], j4 = Jr[4], j5 = Jr[5];
        float jv[6] = {j0, j1, j2, j3, j4, j5};
        int q = 0;
        #pragma unroll
        for (int i = 0; i < 6; ++i)
            #pragma unroll
            for (int jj = i; jj < 6; ++jj) h[q++] += jv[i] * jv[jj];
    }
    #pragma unroll
    for (int q = 0; q < 21; ++q) red[tx][q] = h[q];
    __syncthreads();
    for (int s = 128; s > 0; s >>= 1) {
        if (tx < s)
            for (int q = 0; q < 21; ++q) red[tx][q] += red[tx + s][q];
        __syncthreads();
    }
    if (tx == 0) {
        float H[6][6];
        int q = 0;
        for (int i = 0; i < 6; ++i)
            for (int jj = i; jj < 6; ++jj) { H[i][jj] = red[0][q]; H[jj][i] = red[0][q]; ++q; }
        float A[6][12];
        for (int i = 0; i < 6; ++i)
            for (int jj = 0; jj < 12; ++jj)
                A[i][jj] = (jj < 6) ? H[i][jj] : ((jj - 6 == i) ? 1.f : 0.f);
        for (int col = 0; col < 6; ++col) {
            int piv = col;
            float pv = fabsf(A[col][col]);
            for (int r2 = col + 1; r2 < 6; ++r2) {
                float av = fabsf(A[r2][col]);
                if (av > pv) { pv = av; piv = r2; }
            }
            if (piv != col)
                for (int jj = 0; jj < 12; ++jj) { float tmp = A[col][jj]; A[col][jj] = A[piv][jj]; A[piv][jj] = tmp; }
            float inv = 1.f / A[col][col];
            for (int jj = 0; jj < 12; ++jj) A[col][jj] *= inv;
            for (int r2 = 0; r2 < 6; ++r2) {
                if (r2 == col) continue;
                float f = A[r2][col];
                for (int jj = 0; jj < 12; ++jj) A[r2][jj] -= f * A[col][jj];
            }
        }
        for (int i = 0; i < 6; ++i)
            for (int jj = 0; jj < 6; ++jj) hinv[i * 6 + jj] = A[i][jj + 6];
    }
    __syncthreads();
    for (int k = tx; k < K_; k += 256) {
        const float* Jr = J + (b * K_ + k) * 6;
        float j0 = Jr[0], j1 = Jr[1], j2 = Jr[2], j3 = Jr[3], j4 = Jr[4], j5 = Jr[5];
        #pragma unroll
        for (int i = 0; i < 6; ++i) {
            float s = hinv[i * 6 + 0] * j0 + hinv[i * 6 + 1] * j1 + hinv[i * 6 + 2] * j2
                    + hinv[i * 6 + 3] * j3 + hinv[i * 6 + 4] * j4 + hinv[i * 6 + 5] * j5;
            pinv[(b * 6 + i) * K_ + k] = s;
        }
    }
}

// dx[b,i] = sum_k pinv[b,i,k] * r[b,k]
__global__ void k_dx(const float* __restrict__ pinv, const float* __restrict__ r,
                     float* __restrict__ dx) {
    int b = blockIdx.x;
    int tx = threadIdx.x;
    __shared__ float red[256][6];
    float acc[6] = {0.f, 0.f, 0.f, 0.f, 0.f, 0.f};
    for (int k = tx; k < K_; k += 256) {
        float rv_ = r[b * K_ + k];
        #pragma unroll
        for (int i = 0; i < 6; ++i) acc[i] += pinv[(b * 6 + i) * K_ + k] * rv_;
    }
    #pragma unroll
    for (int i = 0; i < 6; ++i) red[tx][i] = acc[i];
    __syncthreads();
    for (int s = 128; s > 0; s >>= 1) {
        if (tx < s)
            #pragma unroll
            for (int i = 0; i < 6; ++i) red[tx][i] += red[tx + s][i];
        __syncthreads();
    }
    if (tx < 6) dx[b * 6 + tx] = red[0][tx];
}

// conv check + g <- expmap(dx) @ g
__global__ void k_update(const float* __restrict__ dx, float* __restrict__ g) {
    __shared__ float nrm[8];
    __shared__ int sconv;
    int tx = threadIdx.x;
    if (tx < B_) {
        const float* d = dx + tx * 6;
        nrm[tx] = sqrtf(d[0]*d[0] + d[1]*d[1] + d[2]*d[2] + d[3]*d[3] + d[4]*d[4] + d[5]*d[5]);
    }
    __syncthreads();
    if (tx == 0) {
        float m = nrm[0];
        for (int i = 1; i < B_; ++i) m = fmaxf(m, nrm[i]);
        sconv = (m < XTOL_) ? 1 : 0;
    }
    __syncthreads();
    if (sconv) return;
    if (tx < B_) {
        const float* d = dx + tx * 6;
        float wx = d[0], wy = d[1], wz = d[2], vx = d[3], vy = d[4], vz = d[5];
        float t2 = wx*wx + wy*wy + wz*wz;
        float t = sqrtf(t2);
        float s1, s2, s3;
        if (t < 1e-4f) {
            s1 = 1.f - t2 / 6.f;
            s2 = 0.5f - t2 / 24.f;
            s3 = 1.f / 6.f - t2 / 120.f;
        } else {
            float st = sinf(t), ct = cosf(t);
            s1 = st / t;
            s2 = (1.f - ct) / t2;
            s3 = (t - st) / (t2 * t);
        }
        float W[3][3] = {{0.f, -wz, wy}, {wz, 0.f, -wx}, {-wy, wx, 0.f}};
        float S[3][3];
        for (int i = 0; i < 3; ++i)
            for (int j = 0; j < 3; ++j)
                S[i][j] = W[i][0]*W[0][j] + W[i][1]*W[1][j] + W[i][2]*W[2][j];
        float R[3][3], V[3][3];
        for (int i = 0; i < 3; ++i)
            for (int j = 0; j < 3; ++j) {
                float id = (i == j) ? 1.f : 0.f;
                R[i][j] = id + s1 * W[i][j] + s2 * S[i][j];
                V[i][j] = id + s2 * W[i][j] + s3 * S[i][j];
            }
        float p[3];
        for (int i = 0; i < 3; ++i) p[i] = V[i][0]*vx + V[i][1]*vy + V[i][2]*vz;
        float* gb = g + tx * 16;
        float go[16];
        for (int i = 0; i < 16; ++i) go[i] = gb[i];
        // g_new = [[R,p],[0,0,0,1]] @ g_old
        for (int i = 0; i < 3; ++i)
            for (int j = 0; j < 4; ++j)
                gb[i * 4 + j] = R[i][0]*go[0*4+j] + R[i][1]*go[1*4+j] + R[i][2]*go[2*4+j] + p[i]*go[3*4+j];
        // row 3 of g_old is (0,0,0,1) and row 3 of G is (0,0,0,1): unchanged
    }
}

extern "C" void kernel_launch(void* const* d_in, const int* in_sizes, int n_in,
                              void* d_out, int out_size, void* d_ws, size_t ws_size,
                              hipStream_t stream) {
    const float* p0  = (const float*)d_in[0];
    const float* p1  = (const float*)d_in[1];
    const float* W1  = (const float*)d_in[2];
    const float* b1  = (const float*)d_in[3];
    const float* ga1 = (const float*)d_in[4];
    const float* be1 = (const float*)d_in[5];
    const float* rm1 = (const float*)d_in[6];
    const float* rv1 = (const float*)d_in[7];
    const float* W2  = (const float*)d_in[8];
    const float* b2  = (const float*)d_in[9];
    const float* ga2 = (const float*)d_in[10];
    const float* be2 = (const float*)d_in[11];
    const float* rm2 = (const float*)d_in[12];
    const float* rv2 = (const float*)d_in[13];
    const float* W3  = (const float*)d_in[14];
    const float* b3  = (const float*)d_in[15];
    const float* ga3 = (const float*)d_in[16];
    const float* be3 = (const float*)d_in[17];
    const float* rm3 = (const float*)d_in[18];
    const float* rv3 = (const float*)d_in[19];
    // d_in[20] = maxiter (fixed at 10 in setup)

    float* ws   = (float*)d_ws;
    float* g    = ws + OFF_G;
    float* dxb  = ws + OFF_DX;
    float* f0   = ws + OFF_F0;
    int*   idx  = (int*)(ws + OFF_IDX);
    float* act1 = ws + OFF_ACT1;
    float* act2 = ws + OFF_ACT2;
    float* Jb   = ws + OFF_J;
    float* pinv = ws + OFF_PINV;
    float* out  = (float*)d_out;

    dim3 gridN(N_ / 256, B_);
    dim3 grid3(K_ / 32, B_);

    k_init_g<<<1, 128, 0, stream>>>(g);

    // f0 phase (g = I, so transform(p0) == p0 exactly)
    k_layer1<<<gridN, 256, 0, stream>>>(p0, g, W1, b1, ga1, be1, rm1, rv1, act1);
    k_layer2<<<gridN, 256, 0, stream>>>(act1, W2, b2, ga2, be2, rm2, rv2, act2);
    k_layer3<0><<<grid3, 128, 0, stream>>>(act2, W3, b3, ga3, be3, rm3, rv3, nullptr, f0, idx);
    k_jac<<<B_ * K_ / 256, 256, 0, stream>>>(p0, act1, act2, W1, ga1, rv1, W2, ga2, rv2,
                                             W3, ga3, rv3, f0, idx, Jb);
    k_hpinv<<<B_, 256, 0, stream>>>(Jb, pinv);

    for (int it = 0; it < 10; ++it) {
        k_layer1<<<gridN, 256, 0, stream>>>(p1, g, W1, b1, ga1, be1, rm1, rv1, act1);
        k_layer2<<<gridN, 256, 0, stream>>>(act1, W2, b2, ga2, be2, rm2, rv2, act2);
        k_layer3<1><<<grid3, 128, 0, stream>>>(act2, W3, b3, ga3, be3, rm3, rv3, f0, out, nullptr);
        k_dx<<<B_, 256, 0, stream>>>(pinv, out, dxb);
        k_update<<<1, 64, 0, stream>>>(dxb, g);
    }
}

// Round 2
// 1250.005 us; speedup vs baseline: 1.4593x; 1.4593x over previous
//
#include <hip/hip_runtime.h>

#define B_ 8
#define N_ 1024
#define C1_ 64
#define C2_ 128
#define K_ 1024
#define EPS_ 1e-5f
#define XTOL_ 1e-7f

// workspace offsets (in floats)
#define OFF_G     0          // 8*16
#define OFF_F0    128        // 8192
#define OFF_IDX   8320       // 8192 ints
#define OFF_M1    16512      // 8192 u64 (16384 floats)
#define OFF_M2    32896      // 16384 u64 (32768 floats)
#define OFF_ACT2  65664      // 8*128*1024
#define OFF_J     1114240    // 8*1024*6
#define OFF_PINV  1163392    // 8*6*1024
// total 1212544 floats = 4.85 MB

__global__ void k_init_g(float* __restrict__ g) {
    int t = threadIdx.x;
    if (t < B_ * 16) {
        int i = t & 15;
        g[t] = (i == 0 || i == 5 || i == 10 || i == 15) ? 1.f : 0.f;
    }
}

// Fused layer1+layer2 (+SE3 transform). blockIdx.z = which half of the 128
// layer-2 channels this block computes (layer-1 work is duplicated, trivial).
// WRITE_MASKS=1 (f0 phase): also emit sign bitmasks consumed by k_jac.
template<int WRITE_MASKS>
__global__ __launch_bounds__(128)
void k_layer12(const float* __restrict__ pts, const float* __restrict__ g,
               const float* __restrict__ W1, const float* __restrict__ b1,
               const float* __restrict__ ga1, const float* __restrict__ be1,
               const float* __restrict__ rm1, const float* __restrict__ rv1,
               const float* __restrict__ W2, const float* __restrict__ b2,
               const float* __restrict__ ga2, const float* __restrict__ be2,
               const float* __restrict__ rm2, const float* __restrict__ rv2,
               float* __restrict__ act2,
               unsigned long long* __restrict__ m1b,
               unsigned long long* __restrict__ m2b) {
    int b = blockIdx.y;
    int oh = blockIdx.z;
    int n = blockIdx.x * 128 + threadIdx.x;
    const float* gb = g + b * 16;
    float px = pts[(b * N_ + n) * 3 + 0];
    float py = pts[(b * N_ + n) * 3 + 1];
    float pz = pts[(b * N_ + n) * 3 + 2];
    float q0 = gb[0]*px + gb[1]*py + gb[2]*pz  + gb[3];
    float q1 = gb[4]*px + gb[5]*py + gb[6]*pz  + gb[7];
    float q2 = gb[8]*px + gb[9]*py + gb[10]*pz + gb[11];

    float a1[C1_];
    unsigned long long m1 = 0ull;
    #pragma unroll
    for (int c = 0; c < C1_; ++c) {
        float acc = W1[c*3+0]*q0 + W1[c*3+1]*q1 + W1[c*3+2]*q2 + b1[c];
        float sc = ga1[c] * rsqrtf(rv1[c] + EPS_);
        float y = fmaxf(sc * (acc - rm1[c]) + be1[c], 0.f);
        a1[c] = y;
        if (WRITE_MASKS) m1 |= ((unsigned long long)(y > 0.f)) << c;
    }
    if (WRITE_MASKS && oh == 0) m1b[b * N_ + n] = m1;

    unsigned long long m2 = 0ull;
    for (int oo = 0; oo < 64; ++oo) {
        int o = oh * 64 + oo;
        float acc = b2[o];
        #pragma unroll
        for (int c = 0; c < C1_; ++c) acc += W2[o * C1_ + c] * a1[c];
        float sc = ga2[o] * rsqrtf(rv2[o] + EPS_);
        float y = fmaxf(sc * (acc - rm2[o]) + be2[o], 0.f);
        act2[(b * C2_ + o) * N_ + n] = y;
        if (WRITE_MASKS) m2 |= ((unsigned long long)(y > 0.f)) << oo;
    }
    if (WRITE_MASKS) m2b[(b * N_ + n) * 2 + oh] = m2;
}

// layer3 + BN + ReLU + max over n (+argmax MODE 0 / r=f-f0 MODE 1)
// 256 threads, o-tile 32, n-tile 128, c staged in chunks of 32, 4x4 microtile
template <int MODE>
__global__ __launch_bounds__(256)
void k_layer3(const float* __restrict__ act2,
              const float* __restrict__ W3, const float* __restrict__ b3,
              const float* __restrict__ ga, const float* __restrict__ be,
              const float* __restrict__ rm, const float* __restrict__ rv,
              const float* __restrict__ f0, float* __restrict__ out,
              int* __restrict__ out_idx) {
    __shared__ float w3s[C2_][36];   // [c][o_local] transposed, padded
    __shared__ float bs[32][128];    // [c_chunk][n]
    __shared__ float redv[32][32];
    __shared__ int   redi[32][32];

    int b = blockIdx.y;
    int o0 = blockIdx.x * 32;
    int tx = threadIdx.x;
    int og = tx >> 5;       // 0..7  -> o = o0 + og*4 + i
    int ng = tx & 31;       // 0..31 -> n = nbase + ng*4 + j

    // load W3 tile transposed into LDS (once): 32 o x 128 c
    #pragma unroll
    for (int p = 0; p < 4; ++p) {
        int idx = p * 256 + tx;          // 0..1023 float4 slots
        int o = idx >> 5;                // 0..31
        int c4 = (idx & 31) * 4;
        float4 w = *(const float4*)&W3[(o0 + o) * C2_ + c4];
        w3s[c4 + 0][o] = w.x;
        w3s[c4 + 1][o] = w.y;
        w3s[c4 + 2][o] = w.z;
        w3s[c4 + 3][o] = w.w;
    }

    float vmax[4];
    int   vidx[4];
    #pragma unroll
    for (int i = 0; i < 4; ++i) { vmax[i] = -3.4e38f; vidx[i] = 0; }

    for (int nc = 0; nc < 8; ++nc) {
        int nbase = nc * 128;
        float acc[4][4] = {};
        for (int cc = 0; cc < 4; ++cc) {
            __syncthreads();
            // stage act2 chunk: 32c x 128n
            #pragma unroll
            for (int p = 0; p < 4; ++p) {
                int idx = p * 256 + tx;      // 0..1023 float4 slots
                int c = idx >> 5;            // 0..31
                int n4 = (idx & 31) * 4;
                *(float4*)&bs[c][n4] =
                    *(const float4*)&act2[(b * C2_ + cc * 32 + c) * N_ + nbase + n4];
            }
            __syncthreads();
            #pragma unroll 4
            for (int c = 0; c < 32; ++c) {
                float4 a  = *(const float4*)&w3s[cc * 32 + c][og * 4];
                float4 bb = *(const float4*)&bs[c][ng * 4];
                acc[0][0] += a.x * bb.x; acc[0][1] += a.x * bb.y; acc[0][2] += a.x * bb.z; acc[0][3] += a.x * bb.w;
                acc[1][0] += a.y * bb.x; acc[1][1] += a.y * bb.y; acc[1][2] += a.y * bb.z; acc[1][3] += a.y * bb.w;
                acc[2][0] += a.z * bb.x; acc[2][1] += a.z * bb.y; acc[2][2] += a.z * bb.z; acc[2][3] += a.z * bb.w;
                acc[3][0] += a.w * bb.x; acc[3][1] += a.w * bb.y; acc[3][2] += a.w * bb.z; acc[3][3] += a.w * bb.w;
            }
        }
        #pragma unroll
        for (int i = 0; i < 4; ++i) {
            int o = o0 + og * 4 + i;
            float sc = ga[o] * rsqrtf(rv[o] + EPS_);
            float bo = b3[o], rmo = rm[o], beo = be[o];
            #pragma unroll
            for (int j = 0; j < 4; ++j) {
                float y = fmaxf(sc * ((acc[i][j] + bo) - rmo) + beo, 0.f);
                int n = nbase + ng * 4 + j;
                if (y > vmax[i]) { vmax[i] = y; vidx[i] = n; }  // strict > keeps first idx
            }
        }
    }

    __syncthreads();
    #pragma unroll
    for (int i = 0; i < 4; ++i) {
        redv[og * 4 + i][ng] = vmax[i];
        redi[og * 4 + i][ng] = vidx[i];
    }
    __syncthreads();
    if (tx < 32) {
        int o = o0 + tx;
        float bv = redv[tx][0];
        int bi = redi[tx][0];
        for (int q = 1; q < 32; ++q) {
            float v = redv[tx][q];
            int ii = redi[tx][q];
            if (v > bv || (v == bv && ii < bi)) { bv = v; bi = ii; }
        }
        if (MODE == 0) {
            out[b * K_ + o] = bv;
            out_idx[b * K_ + o] = bi;
        } else {
            out[b * K_ + o] = bv - f0[b * K_ + o];
        }
    }
}

// Analytical Jacobian row per (b,k) from sign bitmasks at n* = argmax.
// W1/W2 indices are wave-uniform -> scalar loads; only W3/masks are divergent.
__global__ __launch_bounds__(128)
void k_jac(const float* __restrict__ p0,
           const unsigned long long* __restrict__ m1b,
           const unsigned long long* __restrict__ m2b,
           const float* __restrict__ W1, const float* __restrict__ ga1, const float* __restrict__ rv1,
           const float* __restrict__ W2, const float* __restrict__ ga2, const float* __restrict__ rv2,
           const float* __restrict__ W3, const float* __restrict__ ga3, const float* __restrict__ rv3,
           const float* __restrict__ f0, const int* __restrict__ max_idx,
           float* __restrict__ J) {
    int gid = blockIdx.x * 128 + threadIdx.x;   // 8192
    int b = gid >> 10;
    int k = gid & 1023;
    int ns = max_idx[b * K_ + k];
    unsigned long long m1   = m1b[b * N_ + ns];
    unsigned long long m2lo = m2b[(b * N_ + ns) * 2 + 0];
    unsigned long long m2hi = m2b[(b * N_ + ns) * 2 + 1];
    float D3 = (f0[b * K_ + k] > 0.f) ? ga3[k] * rsqrtf(rv3[k] + EPS_) : 0.f;

    const float* w3r = W3 + k * C2_;
    float v[C1_];
    #pragma unroll
    for (int c = 0; c < C1_; ++c) v[c] = 0.f;

    #pragma unroll 2
    for (int d = 0; d < 64; ++d) {
        float wd = ((m2lo >> d) & 1ull) ? w3r[d] * (ga2[d] * rsqrtf(rv2[d] + EPS_)) : 0.f;
        #pragma unroll
        for (int c = 0; c < C1_; ++c) v[c] += wd * W2[d * C1_ + c];
    }
    #pragma unroll 2
    for (int d = 64; d < C2_; ++d) {
        float wd = ((m2hi >> (d - 64)) & 1ull) ? w3r[d] * (ga2[d] * rsqrtf(rv2[d] + EPS_)) : 0.f;
        #pragma unroll
        for (int c = 0; c < C1_; ++c) v[c] += wd * W2[d * C1_ + c];
    }

    float fj0 = 0.f, fj1 = 0.f, fj2 = 0.f;
    #pragma unroll
    for (int c = 0; c < C1_; ++c) {
        float m = ((m1 >> c) & 1ull) ? ga1[c] * rsqrtf(rv1[c] + EPS_) : 0.f;
        float vc = v[c] * m;
        fj0 += vc * W1[c * 3 + 0];
        fj1 += vc * W1[c * 3 + 1];
        fj2 += vc * W1[c * 3 + 2];
    }
    fj0 *= D3; fj1 *= D3; fj2 *= D3;

    float x = p0[(b * N_ + ns) * 3 + 0];
    float y = p0[(b * N_ + ns) * 3 + 1];
    float z = p0[(b * N_ + ns) * 3 + 2];
    float* Jr = J + (b * K_ + k) * 6;
    Jr[0] = fj1 * (-z) + fj2 * y;
    Jr[1] = fj0 * z    + fj2 * (-x);
    Jr[2] = fj0 * (-y) + fj1 * x;
    Jr[3] = -fj0;
    Jr[4] = -fj1;
    Jr[5] = -fj2;
}

// per-b: H = J^T J (6x6), invert (Gauss-Jordan w/ partial pivot), pinv = Hinv @ J^T
__global__ void k_hpinv(const float* __restrict__ J, float* __restrict__ pinv) {
    int b = blockIdx.x;
    int tx = threadIdx.x;
    __shared__ float red[256][22];
    __shared__ float hinv[36];

    float h[21];
    #pragma unroll
    for (int q = 0; q < 21; ++q) h[q] = 0.f;
    for (int k = tx; k < K_; k += 256) {
        const float* Jr = J + (b * K_ + k) * 6;
        float jv[6] = {Jr[0], Jr[1], Jr[2], Jr[3], Jr[4], Jr[5]};
        int q = 0;
        #pragma unroll
        for (int i = 0; i < 6; ++i)
            #pragma unroll
            for (int jj = i; jj < 6; ++jj) h[q++] += jv[i] * jv[jj];
    }
    #pragma unroll
    for (int q = 0; q < 21; ++q) red[tx][q] = h[q];
    __syncthreads();
    for (int s = 128; s > 0; s >>= 1) {
        if (tx < s)
            for (int q = 0; q < 21; ++q) red[tx][q] += red[tx + s][q];
        __syncthreads();
    }
    if (tx == 0) {
        float H[6][6];
        int q = 0;
        for (int i = 0; i < 6; ++i)
            for (int jj = i; jj < 6; ++jj) { H[i][jj] = red[0][q]; H[jj][i] = red[0][q]; ++q; }
        float A[6][12];
        for (int i = 0; i < 6; ++i)
            for (int jj = 0; jj < 12; ++jj)
                A[i][jj] = (jj < 6) ? H[i][jj] : ((jj - 6 == i) ? 1.f : 0.f);
        for (int col = 0; col < 6; ++col) {
            int piv = col;
            float pv = fabsf(A[col][col]);
            for (int r2 = col + 1; r2 < 6; ++r2) {
                float av = fabsf(A[r2][col]);
                if (av > pv) { pv = av; piv = r2; }
            }
            if (piv != col)
                for (int jj = 0; jj < 12; ++jj) { float tmp = A[col][jj]; A[col][jj] = A[piv][jj]; A[piv][jj] = tmp; }
            float inv = 1.f / A[col][col];
            for (int jj = 0; jj < 12; ++jj) A[col][jj] *= inv;
            for (int r2 = 0; r2 < 6; ++r2) {
                if (r2 == col) continue;
                float f = A[r2][col];
                for (int jj = 0; jj < 12; ++jj) A[r2][jj] -= f * A[col][jj];
            }
        }
        for (int i = 0; i < 6; ++i)
            for (int jj = 0; jj < 6; ++jj) hinv[i * 6 + jj] = A[i][jj + 6];
    }
    __syncthreads();
    for (int k = tx; k < K_; k += 256) {
        const float* Jr = J + (b * K_ + k) * 6;
        float j0 = Jr[0], j1 = Jr[1], j2 = Jr[2], j3 = Jr[3], j4 = Jr[4], j5 = Jr[5];
        #pragma unroll
        for (int i = 0; i < 6; ++i) {
            float s = hinv[i * 6 + 0] * j0 + hinv[i * 6 + 1] * j1 + hinv[i * 6 + 2] * j2
                    + hinv[i * 6 + 3] * j3 + hinv[i * 6 + 4] * j4 + hinv[i * 6 + 5] * j5;
            pinv[(b * 6 + i) * K_ + k] = s;
        }
    }
}

// Fused: dx = pinv @ r (wave per batch), conv check, g <- expmap(dx) @ g
__global__ void k_dxupd(const float* __restrict__ pinv, const float* __restrict__ r,
                        float* __restrict__ g) {
    __shared__ float dxs[B_][6];
    __shared__ float nrm[B_];
    __shared__ int sconv;
    int tx = threadIdx.x;
    int w = tx >> 6;     // batch
    int l = tx & 63;     // lane
    float acc[6] = {0.f, 0.f, 0.f, 0.f, 0.f, 0.f};
    for (int kk = l; kk < K_; kk += 64) {
        float rv_ = r[w * K_ + kk];
        #pragma unroll
        for (int i = 0; i < 6; ++i) acc[i] += pinv[(w * 6 + i) * K_ + kk] * rv_;
    }
    #pragma unroll
    for (int i = 0; i < 6; ++i)
        for (int off = 32; off > 0; off >>= 1) acc[i] += __shfl_down(acc[i], off);
    if (l == 0) {
        #pragma unroll
        for (int i = 0; i < 6; ++i) dxs[w][i] = acc[i];
        nrm[w] = sqrtf(acc[0]*acc[0] + acc[1]*acc[1] + acc[2]*acc[2]
                     + acc[3]*acc[3] + acc[4]*acc[4] + acc[5]*acc[5]);
    }
    __syncthreads();
    if (tx == 0) {
        float m = nrm[0];
        for (int i = 1; i < B_; ++i) m = fmaxf(m, nrm[i]);
        sconv = (m < XTOL_) ? 1 : 0;
    }
    __syncthreads();
    if (sconv) return;
    if (l == 0) {
        float wx = dxs[w][0], wy = dxs[w][1], wz = dxs[w][2];
        float vx = dxs[w][3], vy = dxs[w][4], vz = dxs[w][5];
        float t2 = wx*wx + wy*wy + wz*wz;
        float t = sqrtf(t2);
        float s1, s2, s3;
        if (t < 1e-4f) {
            s1 = 1.f - t2 / 6.f;
            s2 = 0.5f - t2 / 24.f;
            s3 = 1.f / 6.f - t2 / 120.f;
        } else {
            float st = sinf(t), ct = cosf(t);
            s1 = st / t;
            s2 = (1.f - ct) / t2;
            s3 = (t - st) / (t2 * t);
        }
        float W[3][3] = {{0.f, -wz, wy}, {wz, 0.f, -wx}, {-wy, wx, 0.f}};
        float S[3][3];
        for (int i = 0; i < 3; ++i)
            for (int j = 0; j < 3; ++j)
                S[i][j] = W[i][0]*W[0][j] + W[i][1]*W[1][j] + W[i][2]*W[2][j];
        float R[3][3], V[3][3];
        for (int i = 0; i < 3; ++i)
            for (int j = 0; j < 3; ++j) {
                float id = (i == j) ? 1.f : 0.f;
                R[i][j] = id + s1 * W[i][j] + s2 * S[i][j];
                V[i][j] = id + s2 * W[i][j] + s3 * S[i][j];
            }
        float p[3];
        for (int i = 0; i < 3; ++i) p[i] = V[i][0]*vx + V[i][1]*vy + V[i][2]*vz;
        float* gb = g + w * 16;
        float go[16];
        for (int i = 0; i < 16; ++i) go[i] = gb[i];
        for (int i = 0; i < 3; ++i)
            for (int j = 0; j < 4; ++j)
                gb[i * 4 + j] = R[i][0]*go[0*4+j] + R[i][1]*go[1*4+j] + R[i][2]*go[2*4+j] + p[i]*go[3*4+j];
    }
}

extern "C" void kernel_launch(void* const* d_in, const int* in_sizes, int n_in,
                              void* d_out, int out_size, void* d_ws, size_t ws_size,
                              hipStream_t stream) {
    const float* p0  = (const float*)d_in[0];
    const float* p1  = (const float*)d_in[1];
    const float* W1  = (const float*)d_in[2];
    const float* b1  = (const float*)d_in[3];
    const float* ga1 = (const float*)d_in[4];
    const float* be1 = (const float*)d_in[5];
    const float* rm1 = (const float*)d_in[6];
    const float* rv1 = (const float*)d_in[7];
    const float* W2  = (const float*)d_in[8];
    const float* b2  = (const float*)d_in[9];
    const float* ga2 = (const float*)d_in[10];
    const float* be2 = (const float*)d_in[11];
    const float* rm2 = (const float*)d_in[12];
    const float* rv2 = (const float*)d_in[13];
    const float* W3  = (const float*)d_in[14];
    const float* b3  = (const float*)d_in[15];
    const float* ga3 = (const float*)d_in[16];
    const float* be3 = (const float*)d_in[17];
    const float* rm3 = (const float*)d_in[18];
    const float* rv3 = (const float*)d_in[19];
    // d_in[20] = maxiter (fixed at 10 in setup)

    float* ws   = (float*)d_ws;
    float* g    = ws + OFF_G;
    float* f0   = ws + OFF_F0;
    int*   idx  = (int*)(ws + OFF_IDX);
    unsigned long long* m1b = (unsigned long long*)(ws + OFF_M1);
    unsigned long long* m2b = (unsigned long long*)(ws + OFF_M2);
    float* act2 = ws + OFF_ACT2;
    float* Jb   = ws + OFF_J;
    float* pinv = ws + OFF_PINV;
    float* out  = (float*)d_out;

    dim3 grid12(N_ / 128, B_, 2);
    dim3 grid3(K_ / 32, B_);

    k_init_g<<<1, 128, 0, stream>>>(g);

    // f0 phase (g = I -> transform(p0) == p0 exactly)
    k_layer12<1><<<grid12, 128, 0, stream>>>(p0, g, W1, b1, ga1, be1, rm1, rv1,
                                             W2, b2, ga2, be2, rm2, rv2, act2, m1b, m2b);
    k_layer3<0><<<grid3, 256, 0, stream>>>(act2, W3, b3, ga3, be3, rm3, rv3, nullptr, f0, idx);
    k_jac<<<B_ * K_ / 128, 128, 0, stream>>>(p0, m1b, m2b, W1, ga1, rv1, W2, ga2, rv2,
                                             W3, ga3, rv3, f0, idx, Jb);
    k_hpinv<<<B_, 256, 0, stream>>>(Jb, pinv);

    for (int it = 0; it < 10; ++it) {
        k_layer12<0><<<grid12, 128, 0, stream>>>(p1, g, W1, b1, ga1, be1, rm1, rv1,
                                                 W2, b2, ga2, be2, rm2, rv2, act2, nullptr, nullptr);
        k_layer3<1><<<grid3, 256, 0, stream>>>(act2, W3, b3, ga3, be3, rm3, rv3, f0, out, nullptr);
        k_dxupd<<<1, 512, 0, stream>>>(pinv, out, g);
    }
}

// Round 3
// 923.648 us; speedup vs baseline: 1.9749x; 1.3533x over previous
//
#include <hip/hip_runtime.h>

#define B_ 8
#define N_ 1024
#define C1_ 64
#define C2_ 128
#define K_ 1024
#define EPS_ 1e-5f
#define XTOL_ 1e-7f

// workspace offsets (in floats)
#define OFF_G     0          // 8*16
#define OFF_F0    128        // 8192
#define OFF_PM    8320       // 8192 u64 (16384 floats)
#define OFF_M1    24704      // 8192 u64 (16384 floats)
#define OFF_M2    41088      // 8192*4 u32 (32768 floats)
#define OFF_ACT2  73856      // 8*128*1024
#define OFF_J     1122432    // 8*1024*6
#define OFF_PINV  1171584    // 8*6*1024
// total 1220736 floats = 4.88 MB

__global__ void k_init_g(float* __restrict__ g) {
    int t = threadIdx.x;
    if (t < B_ * 16) {
        int i = t & 15;
        g[t] = (i == 0 || i == 5 || i == 10 || i == 15) ? 1.f : 0.f;
    }
}

// Fused layer1+layer2 (+SE3 transform). blockIdx.z = quarter of the 128
// layer-2 channels (layer-1 work duplicated, trivial). Also zeroes pm for
// the upcoming layer3 atomics. WRITE_MASKS=1 (f0 phase): emit sign bitmasks.
template<int WRITE_MASKS>
__global__ __launch_bounds__(128)
void k_layer12(const float* __restrict__ pts, const float* __restrict__ g,
               const float* __restrict__ W1, const float* __restrict__ b1,
               const float* __restrict__ ga1, const float* __restrict__ be1,
               const float* __restrict__ rm1, const float* __restrict__ rv1,
               const float* __restrict__ W2, const float* __restrict__ b2,
               const float* __restrict__ ga2, const float* __restrict__ be2,
               const float* __restrict__ rm2, const float* __restrict__ rv2,
               float* __restrict__ act2,
               unsigned long long* __restrict__ m1b,
               unsigned int* __restrict__ m2q,
               unsigned long long* __restrict__ pm) {
    int b = blockIdx.y;
    int oh = blockIdx.z;           // 0..3, 32 channels each
    int n = blockIdx.x * 128 + threadIdx.x;
    const float* gb = g + b * 16;
    float px = pts[(b * N_ + n) * 3 + 0];
    float py = pts[(b * N_ + n) * 3 + 1];
    float pz = pts[(b * N_ + n) * 3 + 2];
    float q0 = gb[0]*px + gb[1]*py + gb[2]*pz  + gb[3];
    float q1 = gb[4]*px + gb[5]*py + gb[6]*pz  + gb[7];
    float q2 = gb[8]*px + gb[9]*py + gb[10]*pz + gb[11];

    if (oh == 1) pm[b * N_ + n] = 0ull;   // K_ == N_ == 1024

    float a1[C1_];
    unsigned long long m1 = 0ull;
    #pragma unroll
    for (int c = 0; c < C1_; ++c) {
        float acc = W1[c*3+0]*q0 + W1[c*3+1]*q1 + W1[c*3+2]*q2 + b1[c];
        float sc = ga1[c] * rsqrtf(rv1[c] + EPS_);
        float y = fmaxf(sc * (acc - rm1[c]) + be1[c], 0.f);
        a1[c] = y;
        if (WRITE_MASKS) m1 |= ((unsigned long long)(y > 0.f)) << c;
    }
    if (WRITE_MASKS && oh == 0) m1b[b * N_ + n] = m1;

    unsigned int m2 = 0u;
    for (int oo = 0; oo < 32; ++oo) {
        int o = oh * 32 + oo;
        float acc = b2[o];
        #pragma unroll
        for (int c = 0; c < C1_; ++c) acc += W2[o * C1_ + c] * a1[c];
        float sc = ga2[o] * rsqrtf(rv2[o] + EPS_);
        float y = fmaxf(sc * (acc - rm2[o]) + be2[o], 0.f);
        act2[(b * C2_ + o) * N_ + n] = y;
        if (WRITE_MASKS) m2 |= ((unsigned int)(y > 0.f)) << oo;
    }
    if (WRITE_MASKS) m2q[(b * N_ + n) * 4 + oh] = m2;
}

// layer3 + BN + ReLU + block-local max/argmax over a 256-n slab, combined
// across slabs via packed-u64 atomicMax: [f32 bits (y>=0, monotone) | ~n]
// -> max value, first-index tie-break.
__global__ __launch_bounds__(256)
void k_layer3(const float* __restrict__ act2,
              const float* __restrict__ W3, const float* __restrict__ b3,
              const float* __restrict__ ga, const float* __restrict__ be,
              const float* __restrict__ rm, const float* __restrict__ rv,
              unsigned long long* __restrict__ pm) {
    __shared__ float w3s[C2_][36];   // [c][o_local] transposed, padded
    __shared__ float bs[16][256];    // [c_chunk][n]
    __shared__ float redv[32][32];
    __shared__ int   redi[32][32];

    int b = blockIdx.y;
    int o0 = blockIdx.x * 32;
    int nbase = blockIdx.z * 256;
    int tx = threadIdx.x;
    int og = tx >> 5;       // 0..7
    int ng = tx & 31;       // 0..31

    // load W3 tile transposed into LDS (once): 32 o x 128 c
    #pragma unroll
    for (int p = 0; p < 4; ++p) {
        int idx = p * 256 + tx;          // 1024 float4 slots
        int o = idx >> 5;
        int c4 = (idx & 31) * 4;
        float4 w = *(const float4*)&W3[(o0 + o) * C2_ + c4];
        w3s[c4 + 0][o] = w.x;
        w3s[c4 + 1][o] = w.y;
        w3s[c4 + 2][o] = w.z;
        w3s[c4 + 3][o] = w.w;
    }

    float acc[4][8] = {};
    for (int cc = 0; cc < 8; ++cc) {
        __syncthreads();
        // stage act2 chunk: 16c x 256n
        #pragma unroll
        for (int p = 0; p < 4; ++p) {
            int idx = p * 256 + tx;      // 1024 float4 slots
            int c = idx >> 6;            // 0..15
            int n4 = (idx & 63) * 4;
            *(float4*)&bs[c][n4] =
                *(const float4*)&act2[(b * C2_ + cc * 16 + c) * N_ + nbase + n4];
        }
        __syncthreads();
        #pragma unroll
        for (int c = 0; c < 16; ++c) {
            float4 a  = *(const float4*)&w3s[cc * 16 + c][og * 4];
            float4 b0 = *(const float4*)&bs[c][ng * 4];
            float4 b1 = *(const float4*)&bs[c][128 + ng * 4];
            acc[0][0] += a.x * b0.x; acc[0][1] += a.x * b0.y; acc[0][2] += a.x * b0.z; acc[0][3] += a.x * b0.w;
            acc[1][0] += a.y * b0.x; acc[1][1] += a.y * b0.y; acc[1][2] += a.y * b0.z; acc[1][3] += a.y * b0.w;
            acc[2][0] += a.z * b0.x; acc[2][1] += a.z * b0.y; acc[2][2] += a.z * b0.z; acc[2][3] += a.z * b0.w;
            acc[3][0] += a.w * b0.x; acc[3][1] += a.w * b0.y; acc[3][2] += a.w * b0.z; acc[3][3] += a.w * b0.w;
            acc[0][4] += a.x * b1.x; acc[0][5] += a.x * b1.y; acc[0][6] += a.x * b1.z; acc[0][7] += a.x * b1.w;
            acc[1][4] += a.y * b1.x; acc[1][5] += a.y * b1.y; acc[1][6] += a.y * b1.z; acc[1][7] += a.y * b1.w;
            acc[2][4] += a.z * b1.x; acc[2][5] += a.z * b1.y; acc[2][6] += a.z * b1.z; acc[2][7] += a.z * b1.w;
            acc[3][4] += a.w * b1.x; acc[3][5] += a.w * b1.y; acc[3][6] += a.w * b1.z; acc[3][7] += a.w * b1.w;
        }
    }

    float vmax[4];
    int   vidx[4];
    #pragma unroll
    for (int i = 0; i < 4; ++i) { vmax[i] = -3.4e38f; vidx[i] = 0; }
    #pragma unroll
    for (int i = 0; i < 4; ++i) {
        int o = o0 + og * 4 + i;
        float sc = ga[o] * rsqrtf(rv[o] + EPS_);
        float bo = b3[o], rmo = rm[o], beo = be[o];
        #pragma unroll
        for (int j = 0; j < 8; ++j) {      // j<4: n=ng*4+j ; j>=4: n=128+ng*4+j-4
            float y = fmaxf(sc * ((acc[i][j] + bo) - rmo) + beo, 0.f);
            int n = nbase + ((j < 4) ? (ng * 4 + j) : (128 + ng * 4 + (j - 4)));
            if (y > vmax[i]) { vmax[i] = y; vidx[i] = n; }  // increasing n: strict > keeps first
        }
    }

    __syncthreads();
    #pragma unroll
    for (int i = 0; i < 4; ++i) {
        redv[og * 4 + i][ng] = vmax[i];
        redi[og * 4 + i][ng] = vidx[i];
    }
    __syncthreads();
    if (tx < 32) {
        float bv = redv[tx][0];
        int bi = redi[tx][0];
        for (int q = 1; q < 32; ++q) {
            float v = redv[tx][q];
            int ii = redi[tx][q];
            if (v > bv || (v == bv && ii < bi)) { bv = v; bi = ii; }
        }
        unsigned long long pk =
            ((unsigned long long)__float_as_uint(bv) << 32) | (unsigned int)(~(unsigned int)bi);
        atomicMax(&pm[b * K_ + o0 + tx], pk);
    }
}

// Analytical Jacobian: one wave per (b,k). lane = layer-1 channel c.
// Unpacks f0 + argmax from pm; writes f0 and J.
__global__ __launch_bounds__(256)
void k_jac(const float* __restrict__ p0,
           const unsigned long long* __restrict__ m1b,
           const unsigned int* __restrict__ m2q,
           const float* __restrict__ W1, const float* __restrict__ ga1, const float* __restrict__ rv1,
           const float* __restrict__ W2, const float* __restrict__ ga2, const float* __restrict__ rv2,
           const float* __restrict__ W3, const float* __restrict__ ga3, const float* __restrict__ rv3,
           const unsigned long long* __restrict__ pm,
           float* __restrict__ f0, float* __restrict__ J) {
    __shared__ float wvs[4][128];
    int tx = threadIdx.x;
    int wv = tx >> 6;
    int l = tx & 63;
    int w = blockIdx.x * 4 + wv;     // 0..8191
    int b = w >> 10;
    int k = w & 1023;

    unsigned long long pk = pm[b * K_ + k];
    float f0v = __uint_as_float((unsigned int)(pk >> 32));
    int ns = (int)(~(unsigned int)pk);
    if (l == 0) f0[b * K_ + k] = f0v;

    unsigned long long m1 = m1b[b * N_ + ns];
    const unsigned int* mq = m2q + (b * N_ + ns) * 4;
    unsigned int qa = mq[0], qb = mq[1], qc = mq[2], qd = mq[3];
    unsigned int blo = (l < 32) ? (qa >> l) : (qb >> (l - 32));
    unsigned int bhi = (l < 32) ? (qc >> l) : (qd >> (l - 32));

    const float* w3r = W3 + k * C2_;
    float s2a = ga2[l] * rsqrtf(rv2[l] + EPS_);
    float s2b = ga2[64 + l] * rsqrtf(rv2[64 + l] + EPS_);
    float wa = (blo & 1u) ? w3r[l] * s2a : 0.f;
    float wb = (bhi & 1u) ? w3r[64 + l] * s2b : 0.f;
    wvs[wv][l] = wa;
    wvs[wv][64 + l] = wb;
    __syncthreads();

    float v = 0.f;
    #pragma unroll 8
    for (int d = 0; d < C2_; ++d) v += wvs[wv][d] * W2[d * C1_ + l];

    float d1l = ((m1 >> l) & 1ull) ? ga1[l] * rsqrtf(rv1[l] + EPS_) : 0.f;
    float vc = v * d1l;
    float fj0 = vc * W1[l * 3 + 0];
    float fj1 = vc * W1[l * 3 + 1];
    float fj2 = vc * W1[l * 3 + 2];
    #pragma unroll
    for (int off = 32; off; off >>= 1) {
        fj0 += __shfl_xor(fj0, off);
        fj1 += __shfl_xor(fj1, off);
        fj2 += __shfl_xor(fj2, off);
    }
    if (l == 0) {
        float D3 = (f0v > 0.f) ? ga3[k] * rsqrtf(rv3[k] + EPS_) : 0.f;
        fj0 *= D3; fj1 *= D3; fj2 *= D3;
        float x = p0[(b * N_ + ns) * 3 + 0];
        float y = p0[(b * N_ + ns) * 3 + 1];
        float z = p0[(b * N_ + ns) * 3 + 2];
        float* Jr = J + (b * K_ + k) * 6;
        Jr[0] = fj1 * (-z) + fj2 * y;
        Jr[1] = fj0 * z    + fj2 * (-x);
        Jr[2] = fj0 * (-y) + fj1 * x;
        Jr[3] = -fj0;
        Jr[4] = -fj1;
        Jr[5] = -fj2;
    }
}

// per-b: H = J^T J (6x6), pivotless Gauss-Jordan (H is SPD), pinv = Hinv @ J^T
// All inversion indices compile-time -> registers (no scratch).
__global__ void k_hpinv(const float* __restrict__ J, float* __restrict__ pinv) {
    int b = blockIdx.x;
    int tx = threadIdx.x;
    __shared__ float red[256][22];
    __shared__ float hinv[36];

    float h[21];
    #pragma unroll
    for (int q = 0; q < 21; ++q) h[q] = 0.f;
    for (int k = tx; k < K_; k += 256) {
        const float* Jr = J + (b * K_ + k) * 6;
        float jv[6] = {Jr[0], Jr[1], Jr[2], Jr[3], Jr[4], Jr[5]};
        int q = 0;
        #pragma unroll
        for (int i = 0; i < 6; ++i)
            #pragma unroll
            for (int jj = i; jj < 6; ++jj) h[q++] += jv[i] * jv[jj];
    }
    #pragma unroll
    for (int q = 0; q < 21; ++q) red[tx][q] = h[q];
    __syncthreads();
    for (int s = 128; s > 0; s >>= 1) {
        if (tx < s)
            for (int q = 0; q < 21; ++q) red[tx][q] += red[tx + s][q];
        __syncthreads();
    }
    if (tx == 0) {
        float A[6][6], Inv[6][6];
        {
            int q = 0;
            #pragma unroll
            for (int i = 0; i < 6; ++i)
                #pragma unroll
                for (int jj = i; jj < 6; ++jj) { A[i][jj] = red[0][q]; A[jj][i] = red[0][q]; ++q; }
        }
        #pragma unroll
        for (int i = 0; i < 6; ++i)
            #pragma unroll
            for (int jj = 0; jj < 6; ++jj) Inv[i][jj] = (i == jj) ? 1.f : 0.f;
        #pragma unroll
        for (int col = 0; col < 6; ++col) {
            float ipv = 1.f / A[col][col];
            #pragma unroll
            for (int jj = 0; jj < 6; ++jj) { A[col][jj] *= ipv; Inv[col][jj] *= ipv; }
            #pragma unroll
            for (int r2 = 0; r2 < 6; ++r2) {
                if (r2 == col) continue;
                float f = A[r2][col];
                #pragma unroll
                for (int jj = 0; jj < 6; ++jj) {
                    A[r2][jj]   -= f * A[col][jj];
                    Inv[r2][jj] -= f * Inv[col][jj];
                }
            }
        }
        #pragma unroll
        for (int i = 0; i < 6; ++i)
            #pragma unroll
            for (int jj = 0; jj < 6; ++jj) hinv[i * 6 + jj] = Inv[i][jj];
    }
    __syncthreads();
    for (int k = tx; k < K_; k += 256) {
        const float* Jr = J + (b * K_ + k) * 6;
        float j0 = Jr[0], j1 = Jr[1], j2 = Jr[2], j3 = Jr[3], j4 = Jr[4], j5 = Jr[5];
        #pragma unroll
        for (int i = 0; i < 6; ++i) {
            float s = hinv[i * 6 + 0] * j0 + hinv[i * 6 + 1] * j1 + hinv[i * 6 + 2] * j2
                    + hinv[i * 6 + 3] * j3 + hinv[i * 6 + 4] * j4 + hinv[i * 6 + 5] * j5;
            pinv[(b * 6 + i) * K_ + k] = s;
        }
    }
}

// Fused: unpack r = f(pm) - f0 (writes final output), dx = pinv @ r,
// conv check, g <- expmap(dx) @ g.
__global__ void k_dxupd(const unsigned long long* __restrict__ pm,
                        const float* __restrict__ f0,
                        const float* __restrict__ pinv,
                        float* __restrict__ out, float* __restrict__ g) {
    __shared__ float dxs[B_][6];
    __shared__ float nrm[B_];
    __shared__ int sconv;
    int tx = threadIdx.x;
    int w = tx >> 6;     // batch
    int l = tx & 63;     // lane
    float acc[6] = {0.f, 0.f, 0.f, 0.f, 0.f, 0.f};
    for (int kk = l; kk < K_; kk += 64) {
        float fv = __uint_as_float((unsigned int)(pm[w * K_ + kk] >> 32));
        float rv_ = fv - f0[w * K_ + kk];
        out[w * K_ + kk] = rv_;
        #pragma unroll
        for (int i = 0; i < 6; ++i) acc[i] += pinv[(w * 6 + i) * K_ + kk] * rv_;
    }
    #pragma unroll
    for (int i = 0; i < 6; ++i)
        for (int off = 32; off > 0; off >>= 1) acc[i] += __shfl_down(acc[i], off);
    if (l == 0) {
        #pragma unroll
        for (int i = 0; i < 6; ++i) dxs[w][i] = acc[i];
        nrm[w] = sqrtf(acc[0]*acc[0] + acc[1]*acc[1] + acc[2]*acc[2]
                     + acc[3]*acc[3] + acc[4]*acc[4] + acc[5]*acc[5]);
    }
    __syncthreads();
    if (tx == 0) {
        float m = nrm[0];
        for (int i = 1; i < B_; ++i) m = fmaxf(m, nrm[i]);
        sconv = (m < XTOL_) ? 1 : 0;
    }
    __syncthreads();
    if (sconv) return;
    if (l == 0) {
        float wx = dxs[w][0], wy = dxs[w][1], wz = dxs[w][2];
        float vx = dxs[w][3], vy = dxs[w][4], vz = dxs[w][5];
        float t2 = wx*wx + wy*wy + wz*wz;
        float t = sqrtf(t2);
        float s1, s2, s3;
        if (t < 1e-4f) {
            s1 = 1.f - t2 / 6.f;
            s2 = 0.5f - t2 / 24.f;
            s3 = 1.f / 6.f - t2 / 120.f;
        } else {
            float st = sinf(t), ct = cosf(t);
            s1 = st / t;
            s2 = (1.f - ct) / t2;
            s3 = (t - st) / (t2 * t);
        }
        float W[3][3] = {{0.f, -wz, wy}, {wz, 0.f, -wx}, {-wy, wx, 0.f}};
        float S[3][3];
        #pragma unroll
        for (int i = 0; i < 3; ++i)
            #pragma unroll
            for (int j = 0; j < 3; ++j)
                S[i][j] = W[i][0]*W[0][j] + W[i][1]*W[1][j] + W[i][2]*W[2][j];
        float R[3][3], V[3][3];
        #pragma unroll
        for (int i = 0; i < 3; ++i)
            #pragma unroll
            for (int j = 0; j < 3; ++j) {
                float id = (i == j) ? 1.f : 0.f;
                R[i][j] = id + s1 * W[i][j] + s2 * S[i][j];
                V[i][j] = id + s2 * W[i][j] + s3 * S[i][j];
            }
        float p[3];
        #pragma unroll
        for (int i = 0; i < 3; ++i) p[i] = V[i][0]*vx + V[i][1]*vy + V[i][2]*vz;
        float* gb = g + w * 16;
        float go[16];
        #pragma unroll
        for (int i = 0; i < 16; ++i) go[i] = gb[i];
        #pragma unroll
        for (int i = 0; i < 3; ++i)
            #pragma unroll
            for (int j = 0; j < 4; ++j)
                gb[i * 4 + j] = R[i][0]*go[0*4+j] + R[i][1]*go[1*4+j] + R[i][2]*go[2*4+j] + p[i]*go[3*4+j];
    }
}

extern "C" void kernel_launch(void* const* d_in, const int* in_sizes, int n_in,
                              void* d_out, int out_size, void* d_ws, size_t ws_size,
                              hipStream_t stream) {
    const float* p0  = (const float*)d_in[0];
    const float* p1  = (const float*)d_in[1];
    const float* W1  = (const float*)d_in[2];
    const float* b1  = (const float*)d_in[3];
    const float* ga1 = (const float*)d_in[4];
    const float* be1 = (const float*)d_in[5];
    const float* rm1 = (const float*)d_in[6];
    const float* rv1 = (const float*)d_in[7];
    const float* W2  = (const float*)d_in[8];
    const float* b2  = (const float*)d_in[9];
    const float* ga2 = (const float*)d_in[10];
    const float* be2 = (const float*)d_in[11];
    const float* rm2 = (const float*)d_in[12];
    const float* rv2 = (const float*)d_in[13];
    const float* W3  = (const float*)d_in[14];
    const float* b3  = (const float*)d_in[15];
    const float* ga3 = (const float*)d_in[16];
    const float* be3 = (const float*)d_in[17];
    const float* rm3 = (const float*)d_in[18];
    const float* rv3 = (const float*)d_in[19];
    // d_in[20] = maxiter (fixed at 10 in setup)

    float* ws   = (float*)d_ws;
    float* g    = ws + OFF_G;
    float* f0   = ws + OFF_F0;
    unsigned long long* pm  = (unsigned long long*)(ws + OFF_PM);
    unsigned long long* m1b = (unsigned long long*)(ws + OFF_M1);
    unsigned int*       m2q = (unsigned int*)(ws + OFF_M2);
    float* act2 = ws + OFF_ACT2;
    float* Jb   = ws + OFF_J;
    float* pinv = ws + OFF_PINV;
    float* out  = (float*)d_out;

    dim3 grid12(N_ / 128, B_, 4);
    dim3 grid3(K_ / 32, B_, 4);

    k_init_g<<<1, 128, 0, stream>>>(g);

    // f0 phase (g = I -> transform(p0) == p0 exactly)
    k_layer12<1><<<grid12, 128, 0, stream>>>(p0, g, W1, b1, ga1, be1, rm1, rv1,
                                             W2, b2, ga2, be2, rm2, rv2, act2, m1b, m2q, pm);
    k_layer3<<<grid3, 256, 0, stream>>>(act2, W3, b3, ga3, be3, rm3, rv3, pm);
    k_jac<<<B_ * K_ / 4, 256, 0, stream>>>(p0, m1b, m2q, W1, ga1, rv1, W2, ga2, rv2,
                                           W3, ga3, rv3, pm, f0, Jb);
    k_hpinv<<<B_, 256, 0, stream>>>(Jb, pinv);

    for (int it = 0; it < 10; ++it) {
        k_layer12<0><<<grid12, 128, 0, stream>>>(p1, g, W1, b1, ga1, be1, rm1, rv1,
                                                 W2, b2, ga2, be2, rm2, rv2, act2, m1b, m2q, pm);
        k_layer3<<<grid3, 256, 0, stream>>>(act2, W3, b3, ga3, be3, rm3, rv3, pm);
        k_dxupd<<<1, 512, 0, stream>>>(pm, f0, pinv, out, g);
    }
}